// Round 1
// baseline (505.582 us; speedup 1.0000x reference)
//
#include <hip/hip_runtime.h>

#define FDIM 2668

typedef float f32x4 __attribute__((ext_vector_type(4)));
typedef _Float16 f16x8 __attribute__((ext_vector_type(8)));

// ---- packed-B geometry (element counts in f16 halfwords) ----
// G1: userid  K=960  (30 ksteps = 15 supersteps), N=144 (9 tiles): [uu|ui|lin|pad]
// G2: itemid  K=1728 (54 ksteps = 27 supersteps), N=144 (9 tiles): base col 940 (zero-padded tail)
// G3: smalls  K=64   (2 ksteps, staged once),     N=464 (29 tiles)
#define G1_NK 30
#define G2_NK 54
#define G3_NK 2
#define G1_NT 9
#define G2_NT 9
#define G3_NT 29
#define G1_NS 15
#define G2_NS 27

#define HU 0
#define HT (G1_NK * G1_NT * 512)            // 138240
#define HS (HT + G2_NK * G2_NT * 512)       // 387072
#define H_TOTAL (HS + G3_NK * G3_NT * 512)  // 416768 halfwords

#define SUPB (G1_NT * 2048)  // 18432 B: one K=64 superstep image (G1/G2)
#define LDSB (4 * SUPB)      // 73728 B ring; also holds G3's 59392-B single stage

// ---------------- prep: build f16 B-fragment-packed weights in ws ----------------
// layout per region: [kstep][ntile][lane 0:64][j 0:8] ; value = W[k=kb*32+(lane>>4)*8+j][n=nt*16+(lane&15)]
__global__ __launch_bounds__(256) void ffm_prep(
    const float* __restrict__ au_, const float* __restrict__ ai_,
    const float* __restrict__ gu_, const float* __restrict__ gi_,
    const float* __restrict__ ou_, const float* __restrict__ oi_,
    const float* __restrict__ mu_, const float* __restrict__ mi_,
    const float* __restrict__ uu_, const float* __restrict__ ui_,
    const float* __restrict__ tu_, const float* __restrict__ ti_,
    const float* __restrict__ lw, _Float16* __restrict__ ws) {
  int e = blockIdx.x * 256 + threadIdx.x;
  if (e >= H_TOTAL) return;
  float val = 0.f;
  int rel, ntiles;
  if (e < HT) { rel = e; ntiles = G1_NT; }
  else if (e < HS) { rel = e - HT; ntiles = G2_NT; }
  else { rel = e - HS; ntiles = G3_NT; }
  int perk = ntiles * 512;
  int kb = rel / perk;
  int r = rel - kb * perk;
  int nt = r >> 9; r &= 511;
  int lane = r >> 3, j = r & 7;
  int k = kb * 32 + ((lane >> 4) << 3) + j;
  int n = (nt << 4) + (lane & 15);

  if (e < HT) {                               // G1: cols 0..959 (real < 943)
    if (k < 943) {
      if (n < 64) val = uu_[k * 64 + n];
      else if (n < 128) val = ui_[k * 64 + n - 64];
      else if (n == 128) val = lw[k];
    }
  } else if (e < HS) {                        // G2: cols 940..2667 (real 943..2635)
    int col = 940 + k;
    if (n < 64) { if (col >= 943 && col < 2625) val = tu_[(col - 943) * 64 + n]; }
    else if (n < 128) { if (col >= 943 && col < 2625) val = ti_[(col - 943) * 64 + n - 64]; }
    else if (n == 128) { if (col >= 943 && col <= 2635) val = lw[col]; }
  } else {                                    // G3: cols 2624..2687 (real < 2668)
    int col = 2624 + k;
    if (n == 448) { if (col >= 2636 && col < 2668) val = lw[col]; }
    else if (n < 448) {
      int blk = n >> 6, d = n & 63;
      float ageu = (col == 2626) ? au_[d] : 0.f;
      float agei = (col == 2626) ? ai_[d] : 0.f;
      float genu = (col >= 2626 && col < 2628) ? gu_[(col - 2626) * 64 + d] : 0.f;
      float geni = (col >= 2626 && col < 2628) ? gi_[(col - 2626) * 64 + d] : 0.f;
      float occu = (col >= 2628 && col < 2649) ? ou_[(col - 2628) * 64 + d] : 0.f;
      float occi = (col >= 2628 && col < 2649) ? oi_[(col - 2628) * 64 + d] : 0.f;
      float movu = (col >= 2649 && col < 2668) ? mu_[(col - 2649) * 64 + d] : 0.f;
      float movi = (col >= 2649 && col < 2668) ? mi_[(col - 2649) * 64 + d] : 0.f;
      switch (blk) {
        case 0: val = ageu + genu + occu; break;  // P  = au+gu+ou
        case 1: val = agei + geni + occi; break;  // Q0 = ai+gi+oi
        case 2: val = movu; break;                // mu
        case 3: val = movi; break;                // mi
        case 4: val = ageu; break;                // au
        case 5: val = genu; break;                // gu
        case 6: val = occu; break;                // ou
      }
    }
  }
  ws[e] = (_Float16)val;
}

// ---------------- main kernel helpers ----------------
__device__ __forceinline__ void gll16(const _Float16* __restrict__ src, char* dst) {
  __builtin_amdgcn_global_load_lds((const __attribute__((address_space(1))) void*)src,
                                   (__attribute__((address_space(3))) void*)dst, 16, 0, 0);
}

// stage one K=64 superstep image (NT*2048 B) cooperatively; W per wave: w<2 -> 5, else 4 (NT=9)
template <int NT>
__device__ __forceinline__ void stageS(const _Float16* __restrict__ src, char* lds,
                                       int bufOff, int tid, int wave) {
  constexpr int chunks = NT * 128;  // 16B chunks
#pragma unroll
  for (int base = 0; base < chunks; base += 256) {
    int idx = base + tid;
    if (idx < chunks)
      gll16(src + (size_t)idx * 8, lds + bufOff + (base + wave * 64) * 16);
  }
}

__device__ __forceinline__ void loadS(f32x4 (&A)[4], const float* __restrict__ myrow, int cs) {
  A[0] = *(const f32x4*)(myrow + cs);
  A[1] = *(const f32x4*)(myrow + cs + 4);
  A[2] = *(const f32x4*)(myrow + cs + 32);
  A[3] = *(const f32x4*)(myrow + cs + 36);
}

template <bool GUARD>
__device__ __forceinline__ f32x4 ldg4(const float* __restrict__ myrow, int c) {
  f32x4 z = {0.f, 0.f, 0.f, 0.f};
  if (!GUARD || (c + 4) <= FDIM) return *(const f32x4*)(myrow + c);
  return z;
}

// counted-vmcnt sync: steady N=2W+4 (S(k+1)+A(k+1)+S(k+2) stay in flight), tail W+4, last 0.
__device__ __forceinline__ void syncw(int sel, bool hiw) {
  if (sel == 2) {
    if (hiw) asm volatile("s_waitcnt vmcnt(14) lgkmcnt(0)" ::: "memory");
    else     asm volatile("s_waitcnt vmcnt(12) lgkmcnt(0)" ::: "memory");
  } else if (sel == 1) {
    if (hiw) asm volatile("s_waitcnt vmcnt(9) lgkmcnt(0)" ::: "memory");
    else     asm volatile("s_waitcnt vmcnt(8) lgkmcnt(0)" ::: "memory");
  } else {
    asm volatile("s_waitcnt vmcnt(0) lgkmcnt(0)" ::: "memory");
  }
  __builtin_amdgcn_s_barrier();
}

// One pipelined superstep: uses A-slot Au (loaded 2 iters ago), loads A(k+2) into An,
// issues stage(k+3) into ring buf (k+3)&3, computes 2*NT MFMAs on buf k&3.
template <int NT, int NS>
__device__ __forceinline__ void pbody(int k, f32x4 (&Au)[4], f32x4 (&An)[4],
                                      const float* __restrict__ myrow, int colbase,
                                      const _Float16* __restrict__ wsrc, char* lds,
                                      int tid, int lane, int kg, int wave, bool hiw,
                                      f32x4* acc) {
  int sel = (k + 2 < NS) ? 2 : ((k + 1 < NS) ? 1 : 0);
  syncw(sel, hiw);
  if (k + 2 < NS) loadS(An, myrow, colbase + (k + 2) * 64 + kg * 8);
  if (k + 3 < NS)
    stageS<NT>(wsrc + (size_t)(k + 3) * (NT * 1024), lds, ((k + 3) & 3) * SUPB, tid, wave);
  f16x8 af0, af1;
#pragma unroll
  for (int i = 0; i < 4; ++i) {
    af0[i] = (_Float16)Au[0][i]; af0[4 + i] = (_Float16)Au[1][i];
    af1[i] = (_Float16)Au[2][i]; af1[4 + i] = (_Float16)Au[3][i];
  }
  const char* buf = lds + ((k & 3) * SUPB) + lane * 16;
#pragma unroll
  for (int nt = 0; nt < NT; ++nt)
    acc[nt] = __builtin_amdgcn_mfma_f32_16x16x32_f16(
        af0, *(const f16x8*)(buf + nt * 1024), acc[nt], 0, 0, 0);
#pragma unroll
  for (int nt = 0; nt < NT; ++nt)
    acc[nt] = __builtin_amdgcn_mfma_f32_16x16x32_f16(
        af1, *(const f16x8*)(buf + NT * 1024 + nt * 1024), acc[nt], 0, 0, 0);
}

// Full phase: prologue S0 A0 S1 A1 S2, then unroll-by-3 steady loop (static A rotation).
template <int NT, int NS>
__device__ __forceinline__ void phaseP(const float* __restrict__ myrow, int colbase,
                                       const _Float16* __restrict__ wsrc, char* lds,
                                       int tid, int lane, int kg, int wave, bool hiw,
                                       f32x4* acc) {
  static_assert(NS % 3 == 0, "NS must be divisible by 3 for static A rotation");
  f32x4 A0[4], A1[4], A2[4];
  stageS<NT>(wsrc, lds, 0, tid, wave);
  loadS(A0, myrow, colbase + kg * 8);
  stageS<NT>(wsrc + (size_t)(NT * 1024), lds, SUPB, tid, wave);
  loadS(A1, myrow, colbase + 64 + kg * 8);
  stageS<NT>(wsrc + (size_t)2 * (NT * 1024), lds, 2 * SUPB, tid, wave);
  for (int kb = 0; kb < NS; kb += 3) {
    pbody<NT, NS>(kb + 0, A0, A2, myrow, colbase, wsrc, lds, tid, lane, kg, wave, hiw, acc);
    pbody<NT, NS>(kb + 1, A1, A0, myrow, colbase, wsrc, lds, tid, lane, kg, wave, hiw, acc);
    pbody<NT, NS>(kb + 2, A2, A1, myrow, colbase, wsrc, lds, tid, lane, kg, wave, hiw, acc);
  }
}

// ---------------- main kernel ----------------
__global__ __launch_bounds__(256, 2) void ffm_main(
    const float* __restrict__ fv, const _Float16* __restrict__ wp,
    const float* __restrict__ linb, float* __restrict__ out) {
  __shared__ __align__(16) char lds[LDSB];
  const int tid = threadIdx.x;
  const int lane = tid & 63;
  const int wave = tid >> 6;
  const int nl = lane & 15;
  const int kg = lane >> 4;
  const bool hiw = tid < 128;
  const int rowbase = blockIdx.x * 64 + wave * 16;
  const float* myrow = fv + (size_t)(rowbase + nl) * FDIM;
  const f32x4 zero4 = {0.f, 0.f, 0.f, 0.f};

  // ---- G3: both ksteps staged once (59392 B), then 2x29 MFMAs ----
  f32x4 s[G3_NT];
#pragma unroll
  for (int i = 0; i < G3_NT; ++i) s[i] = zero4;
  {
    constexpr int chunks = G3_NT * 64 * G3_NK;  // 3712
#pragma unroll
    for (int base = 0; base < chunks; base += 256) {
      int idx = base + tid;
      if (idx < chunks)
        gll16(wp + HS + (size_t)idx * 8, lds + (base + wave * 64) * 16);
    }
    f32x4 a0 = ldg4<true>(myrow, 2624 + kg * 8);
    f32x4 a1 = ldg4<true>(myrow, 2624 + kg * 8 + 4);
    f32x4 a2 = ldg4<true>(myrow, 2656 + kg * 8);
    f32x4 a3 = ldg4<true>(myrow, 2656 + kg * 8 + 4);
    asm volatile("s_waitcnt vmcnt(0) lgkmcnt(0)" ::: "memory");
    __builtin_amdgcn_s_barrier();
    f16x8 af0, af1;
#pragma unroll
    for (int i = 0; i < 4; ++i) {
      af0[i] = (_Float16)a0[i]; af0[4 + i] = (_Float16)a1[i];
      af1[i] = (_Float16)a2[i]; af1[4 + i] = (_Float16)a3[i];
    }
    const char* buf = lds + lane * 16;
#pragma unroll
    for (int nt = 0; nt < G3_NT; ++nt)
      s[nt] = __builtin_amdgcn_mfma_f32_16x16x32_f16(
          af0, *(const f16x8*)(buf + nt * 1024), s[nt], 0, 0, 0);
#pragma unroll
    for (int nt = 0; nt < G3_NT; ++nt)
      s[nt] = __builtin_amdgcn_mfma_f32_16x16x32_f16(
          af1, *(const f16x8*)(buf + G3_NT * 1024 + nt * 1024), s[nt], 0, 0, 0);
    asm volatile("s_waitcnt lgkmcnt(0)" ::: "memory");
    __builtin_amdgcn_s_barrier();  // all reads done before G1 prologue overwrites
  }

  // fold G3
  f32x4 P[4], Q[4], MU[4], MI[4];
  f32x4 cross = s[28];  // lin partial (cols 2636..2667)
#pragma unroll
  for (int t = 0; t < 4; ++t) {
    P[t] = s[t]; Q[t] = s[4 + t]; MU[t] = s[8 + t]; MI[t] = s[12 + t];
    // smallcross = au·(gu+ou) + gu·ou + mu·Q0
    cross += s[16 + t] * (s[20 + t] + s[24 + t]) + s[20 + t] * s[24 + t] + MU[t] * Q[t];
  }

  // ---- G1: userid -> uu, ui ----
  f32x4 u[G1_NT];
#pragma unroll
  for (int i = 0; i < G1_NT; ++i) u[i] = zero4;
  phaseP<G1_NT, G1_NS>(myrow, 0, wp + HU, lds, tid, lane, kg, wave, hiw, u);
  cross += u[8];  // lin partial cols 0..942
#pragma unroll
  for (int t = 0; t < 4; ++t) {
    cross += u[t] * P[t] + u[4 + t] * MU[t];  // uu·P + ui·mu
    Q[t] += u[4 + t];                          // Q = Q0 + ui
  }
  asm volatile("s_waitcnt lgkmcnt(0)" ::: "memory");
  __builtin_amdgcn_s_barrier();  // all G1 reads done before G2 prologue overwrites

  // ---- G2: itemid -> tu, ti ----
  f32x4 v[G2_NT];
#pragma unroll
  for (int i = 0; i < G2_NT; ++i) v[i] = zero4;
  phaseP<G2_NT, G2_NS>(myrow, 940, wp + HT, lds, tid, lane, kg, wave, hiw, v);
  cross += v[8];  // lin partial cols 943..2635
#pragma unroll
  for (int t = 0; t < 4; ++t)
    cross += v[t] * Q[t] + v[4 + t] * MI[t];  // tu·Q + ti·mi

  // ---- reduce over the 16 d-lanes per row group and store ----
  float c0 = cross[0], c1 = cross[1], c2 = cross[2], c3 = cross[3];
#pragma unroll
  for (int m = 1; m <= 8; m <<= 1) {
    c0 += __shfl_xor(c0, m, 64);
    c1 += __shfl_xor(c1, m, 64);
    c2 += __shfl_xor(c2, m, 64);
    c3 += __shfl_xor(c3, m, 64);
  }
  if (nl == 0) {
    float lb = linb[0];
    int r = rowbase + kg * 4;
    out[r + 0] = 1.f / (1.f + __expf(-(c0 + lb)));
    out[r + 1] = 1.f / (1.f + __expf(-(c1 + lb)));
    out[r + 2] = 1.f / (1.f + __expf(-(c2 + lb)));
    out[r + 3] = 1.f / (1.f + __expf(-(c3 + lb)));
  }
}

extern "C" void kernel_launch(void* const* d_in, const int* in_sizes, int n_in,
                              void* d_out, int out_size, void* d_ws, size_t ws_size,
                              hipStream_t stream) {
  const float* fv    = (const float*)d_in[0];
  const float* age_u = (const float*)d_in[1];
  const float* age_i = (const float*)d_in[2];
  const float* gen_u = (const float*)d_in[3];
  const float* gen_i = (const float*)d_in[4];
  const float* occ_u = (const float*)d_in[5];
  const float* occ_i = (const float*)d_in[6];
  const float* mov_u = (const float*)d_in[7];
  const float* mov_i = (const float*)d_in[8];
  const float* uid_u = (const float*)d_in[9];
  const float* uid_i = (const float*)d_in[10];
  const float* iid_u = (const float*)d_in[11];
  const float* iid_i = (const float*)d_in[12];
  const float* lin_w = (const float*)d_in[13];
  const float* lin_b = (const float*)d_in[14];
  _Float16* ws = (_Float16*)d_ws;
  float* out = (float*)d_out;

  ffm_prep<<<(H_TOTAL + 255) / 256, 256, 0, stream>>>(
      age_u, age_i, gen_u, gen_i, occ_u, occ_i, mov_u, mov_i,
      uid_u, uid_i, iid_u, iid_i, lin_w, ws);
  ffm_main<<<32768 / 64, 256, 0, stream>>>(fv, ws, lin_b, out);
}